// Round 3
// baseline (319.305 us; speedup 1.0000x reference)
//
#include <hip/hip_runtime.h>
#include <math.h>

// Gaussian NLL + analytic grad + Hessian wrt (mu, pre-softplus-std).
// 2 elems/thread, all accesses dwordx2/dwordx4 stride-1 coalesced.
// VALU diet: 1 exp + 2 log + 2 v_rcp per element (no v_div chains).
// Traffic = 40 B/elem * 2^23 = 335 MB -> ~53 us @ 6.3 TB/s.

typedef float f4 __attribute__((ext_vector_type(4)));
typedef float f2 __attribute__((ext_vector_type(2)));

__global__ __launch_bounds__(256) void unll_kernel(
    const f4* __restrict__ yp,     // [N/2] of (mu0,s0,mu1,s1)
    const f2* __restrict__ yt,     // [N/2] of (y0,y1)
    f2* __restrict__ out_loss,     // [N/2]
    f4* __restrict__ out_g,        // [N/2] of (g0mu,g0s,g1mu,g1s)
    f4* __restrict__ out_h,        // [N]   of (h00,h01,h01,h11)
    int nv)                        // N/2
{
    int i = blockIdx.x * blockDim.x + threadIdx.x;
    if (i >= nv) return;

    f4 p = yp[i];
    f2 t = yt[i];

    float mu[2] = {p.x, p.z};
    float sv[2] = {p.y, p.w};
    float yv[2] = {t.x, t.y};

    float L[2], G0[2], G1[2], H00[2], H01[2], H11[2];

#pragma unroll
    for (int k = 0; k < 2; ++k) {
        float s = sv[k];
        float e     = __expf(-fabsf(s));          // exp(-|s|)
        float denom = 1.0f + e;
        float r     = __builtin_amdgcn_rcpf(denom);
        float sig   = (s >= 0.0f) ? r : e * r;    // sigmoid(s)
        float stdv  = fmaxf(s, 0.0f) + __logf(denom); // softplus(s)
        float inv   = __builtin_amdgcn_rcpf(stdv);
        float z     = (yv[k] - mu[k]) * inv;
        float z2    = z * z;

        L[k]  = 0.5f * z2 + __logf(stdv) + 0.91893853320467274178f;
        G0[k] = -z * inv;
        G1[k] = sig * (1.0f - z2) * inv;

        float inv2 = inv * inv;
        H00[k] = inv2;
        H01[k] = 2.0f * z * sig * inv2;
        H11[k] = sig * (1.0f - sig) * (1.0f - z2) * inv
               + sig * sig * (3.0f * z2 - 1.0f) * inv2;
    }

    f2 lo = {L[0], L[1]};
    f4 g  = {G0[0], G1[0], G0[1], G1[1]};
    f4 h0 = {H00[0], H01[0], H01[0], H11[0]};
    f4 h1 = {H00[1], H01[1], H01[1], H11[1]};

    __builtin_nontemporal_store(lo, &out_loss[i]);
    __builtin_nontemporal_store(g,  &out_g[i]);
    __builtin_nontemporal_store(h0, &out_h[2 * i]);
    __builtin_nontemporal_store(h1, &out_h[2 * i + 1]);
}

extern "C" void kernel_launch(void* const* d_in, const int* in_sizes, int n_in,
                              void* d_out, int out_size, void* d_ws, size_t ws_size,
                              hipStream_t stream) {
    const float* y_pred = (const float*)d_in[0];  // [N,2]
    const float* y_true = (const float*)d_in[1];  // [N]
    float* out = (float*)d_out;                   // loss[N] | d[2N] | dd[4N]

    const int N = in_sizes[1];   // 2^23
    const int nv = N / 2;

    f2* out_loss = (f2*)out;
    f4* out_g    = (f4*)(out + (size_t)N);
    f4* out_h    = (f4*)(out + (size_t)3 * N);

    const int block = 256;
    const int grid = (nv + block - 1) / block;
    unll_kernel<<<grid, block, 0, stream>>>(
        (const f4*)y_pred, (const f2*)y_true, out_loss, out_g, out_h, nv);
}